// Round 10
// baseline (510.391 us; speedup 1.0000x reference)
//
#include <hip/hip_runtime.h>
#include <math.h>

// Problem dims (fixed): T=4, B=64, N=256, D=512.
// GEMM rows r = (n*B+b)*T + t == natural row order of mx [N,B,T,D] -> A = mx.
namespace {
constexpr int TDIM = 4, BDIM = 64, NDIM = 256, DDIM = 512;
constexpr int MROWS = 65536;               // N*B*T
constexpr long long BND = 8388608LL;       // B*N*D
constexpr double BN_EPS = 1e-5;

// ---- fallback tiling (small-ws path) ----
constexpr int BM = 64, BNT = 128, BK = 32;
constexpr int APITCH = BK + 2;
constexpr int WPITCH = BNT + 4;
constexpr int LDS_BYTES = (BM * APITCH + BK * WPITCH) * 8;

// ---- f64-MFMA path (R6, proven): 128x64 block, 4 waves of 64x32, BK=16 ----
constexpr int BM3 = 128, BN3 = 64, BK3 = 16;
constexpr int AP3 = BM3 + 1;
constexpr int WP3 = BN3 + 1;

// ---- i8-Ozaki path ----
// A sliced (scale 4) into 6 radix-128 digits; W (scale 256) into 5.
// h = 2^-10 * sum_{g<=5} 128^-g * G_g, G_g = sum_{s+t=g} A_s.W_t (i32-exact).
// Slice planes stored BLOCKED K-MAJOR: plane + tile*32768 + kseg*1024 + ri*16.
constexpr int NSA = 6, NSW = 5;
constexpr long long APL = 33554432LL;      // A plane bytes: 65536*512
constexpr long long WPL = 262144LL;        // W plane bytes: 512*512
constexpr int CH8 = 22528;                 // LDS per buffer: A 6*2048 + W 5*2048
}

typedef double d4 __attribute__((ext_vector_type(4)));
typedef int i32x4 __attribute__((ext_vector_type(4)));
typedef int i32x16 __attribute__((ext_vector_type(16)));

#define GLOAD16(g, d) __builtin_amdgcn_global_load_lds( \
    (const __attribute__((address_space(1))) void*)(g), \
    (__attribute__((address_space(3))) void*)(d), 16, 0, 0)

// ======= probe: D row mapping of v_mfma_f64_16x16x4f64 (f64 path) =======
__global__ void probe_k(double* __restrict__ rowmap)
{
    const int l = threadIdx.x;
    d4 z = {0.0, 0.0, 0.0, 0.0};
    d4 dr = __builtin_amdgcn_mfma_f64_16x16x4f64((double)(l & 15), 1.0, z, 0, 0, 0);
#pragma unroll
    for (int r = 0; r < 4; ++r)
        rowmap[l * 4 + r] = dr[r] * 0.25;
}

// ======= probe: D row/col mapping of v_mfma_i32_32x32x32_i8 =======
__global__ void probe8_k(double* __restrict__ irow8, double* __restrict__ icol8)
{
    const int l = threadIdx.x;      // 64 threads = 1 wave
    i32x16 z;
#pragma unroll
    for (int r = 0; r < 16; ++r) z[r] = 0;
    const int mb = (l & 31) * 0x01010101;
    const int ob = 0x01010101;
    i32x4 am = {mb, mb, mb, mb};
    i32x4 a1 = {ob, ob, ob, ob};
    i32x16 d1 = __builtin_amdgcn_mfma_i32_32x32x32_i8(am, a1, z, 0, 0, 0);
#pragma unroll
    for (int r = 0; r < 16; ++r)
        irow8[l * 16 + r] = (double)d1[r] / 32.0;
    i32x16 d2 = __builtin_amdgcn_mfma_i32_32x32x32_i8(a1, am, z, 0, 0, 0);
    icol8[l] = (double)d2[0] / 32.0;
}

// ======= A slicing -> blocked K-major planes =======
// digit0 in f64; residual V-rint(V) has <=24 significand bits -> exact f32 path.
__global__ __launch_bounds__(256)
void slice_a_k(const float* __restrict__ src, char* __restrict__ dst)
{
    const int ri  = threadIdx.x & 63;
    const int ks0 = threadIdx.x >> 6;          // 0..3
    const long long row = (long long)blockIdx.x * 64 + ri;
#pragma unroll 1
    for (int it = 0; it < 8; ++it) {
        const int kseg = it * 4 + ks0;         // 0..31
        const float* sp = src + row * DDIM + kseg * 16;
        union { char c[16]; i32x4 v; } pk[NSA];
#pragma unroll
        for (int e = 0; e < 16; ++e) {
            const double V = (double)sp[e] * 4.0;
            const double u = rint(V);
            pk[0].c[e] = (char)(int)u;
            float r = (float)(V - u);          // exact
#pragma unroll
            for (int s = 1; s < NSA; ++s) {
                r *= 128.0f;                   // exact (pow2)
                const float uf = rintf(r);
                r -= uf;                       // exact
                pk[s].c[e] = (char)(int)uf;
            }
        }
        const long long base = (long long)blockIdx.x * 32768 + kseg * 1024 + ri * 16;
#pragma unroll
        for (int s = 0; s < NSA; ++s)
            *(i32x4*)(dst + (long long)s * APL + base) = pk[s].v;
    }
}

// ======= W slicing -> blocked K-major planes (8 col tiles) =======
__global__ __launch_bounds__(256)
void slice_w_k(const float* __restrict__ src, char* __restrict__ dst)
{
    const int cbk  = blockIdx.x >> 3;          // 0..7 col tile
    const int kgrp = blockIdx.x & 7;
    const int ci   = threadIdx.x & 63;
    const int kseg = kgrp * 4 + (threadIdx.x >> 6);   // 0..31
    const float* sp = src + (long long)(cbk * 64 + ci) * DDIM + kseg * 16;
    union { char c[16]; i32x4 v; } pk[NSW];
#pragma unroll
    for (int e = 0; e < 16; ++e) {
        const double V = (double)sp[e] * 256.0;
        const double u = rint(V);
        pk[0].c[e] = (char)(int)u;
        float r = (float)(V - u);              // exact
#pragma unroll
        for (int s = 1; s < NSW; ++s) {
            r *= 128.0f;
            const float uf = rintf(r);
            r -= uf;
            pk[s].c[e] = (char)(int)uf;
        }
    }
    const long long base = (long long)cbk * 32768 + kseg * 1024 + ci * 16;
#pragma unroll
    for (int s = 0; s < NSW; ++s)
        *(i32x4*)(dst + (long long)s * WPL + base) = pk[s].v;
}

// ======= per-wave staging: NW windows, pointers advance 2KB/chunk =======
template<int NW>
struct Stager {
    const char* gp[NW];
    int lo[NW];
    __device__ __forceinline__ void init(int w0, const char* Asl, const char* Wsl,
                                         long long aT, long long wT, int l)
    {
#pragma unroll
        for (int i = 0; i < NW; ++i) {
            const int idx = w0 + i;
            if (idx < 12) {
                gp[i] = Asl + (long long)(idx >> 1) * APL + aT
                      + (long long)(idx & 1) * 1024 + l * 16;
                lo[i] = (idx >> 1) * 2048 + (idx & 1) * 1024;
            } else {
                const int e = idx - 12;
                gp[i] = Wsl + (long long)(e >> 1) * WPL + wT
                      + (long long)(e & 1) * 1024 + l * 16;
                lo[i] = 12288 + (e >> 1) * 2048 + (e & 1) * 1024;
            }
        }
    }
    __device__ __forceinline__ void issue(char* buf)
    {
#pragma unroll
        for (int i = 0; i < NW; ++i) {
            GLOAD16(gp[i], buf + lo[i]);
            gp[i] += 2048;
        }
    }
};

// ======= main K-loop: counted vmcnt, raw barriers (T3/T4), setprio (T5) =======
template<int NW>
__device__ __forceinline__ void gemm8_loop(Stager<NW>& st, char* smb,
                                           i32x16 (&acc)[6], int roA, int roW)
{
#pragma unroll 2
    for (int c = 0; c < 16; ++c) {
        const char* bA = smb + (c & 1) * CH8;
        const char* bW = bA + 12288;
        i32x4 af[NSA], wf[NSW];
        // reads in usage order: first MFMA row needs af[0] + wf[t]
        af[0] = *(const i32x4*)(bA + roA);
#pragma unroll
        for (int t = 0; t < NSW; ++t)
            wf[t] = *(const i32x4*)(bW + t * 2048 + roW);
#pragma unroll
        for (int s = 1; s < NSA; ++s)
            af[s] = *(const i32x4*)(bA + s * 2048 + roA);
        __builtin_amdgcn_s_setprio(1);
#pragma unroll
        for (int s = 0; s < NSA; ++s)
#pragma unroll
            for (int t = 0; t < NSW; ++t)
                if (s + t <= 5)
                    acc[s + t] = __builtin_amdgcn_mfma_i32_32x32x32_i8(
                                     af[s], wf[t], acc[s + t], 0, 0, 0);
        __builtin_amdgcn_s_setprio(0);
        if (c == 15) break;
        // all waves done reading buf[c&1] (ds_reads consumed by MFMA issue)
        asm volatile("s_barrier" ::: "memory");
        if (c < 14) {
            st.issue(smb + (c & 1) * CH8);      // batch c+2 -> buf[c&1]
            if constexpr (NW == 6)
                asm volatile("s_waitcnt vmcnt(6)" ::: "memory");  // batch c+1 done
            else
                asm volatile("s_waitcnt vmcnt(5)" ::: "memory");
        } else {
            asm volatile("s_waitcnt vmcnt(0)" ::: "memory");      // tail drain
        }
        __builtin_amdgcn_sched_barrier(0);
        asm volatile("s_barrier" ::: "memory");   // batch c+1 visible to all
        __builtin_amdgcn_sched_barrier(0);
    }
}

// ======= i8-Ozaki exact GEMM: 64x64 block, 4 waves of 32x32 =======
__global__ __launch_bounds__(256, 3)
void gemm8_k(const char* __restrict__ Asl, const char* __restrict__ Wsl,
             double* __restrict__ hbuf, double* __restrict__ sums,
             const double* __restrict__ irow8, const double* __restrict__ icol8)
{
    __shared__ __align__(16) char sm[2][CH8];

    const int tid = threadIdx.x;
    // XCD swizzle: 8 col-blocks of one row-block land on one XCD.
    const int bid = blockIdx.x;                     // 0..8191
    const int rb  = ((bid >> 6) << 3) | (bid & 7);  // 0..1023
    const int cb  = (bid >> 3) & 7;                 // 0..7

    const int w  = tid >> 6;       // wave 0..3
    const int l  = tid & 63;
    const int wr = w >> 1;         // row slab (0..1) -> 32 rows
    const int wc = w & 1;          // col slab (0..1) -> 32 cols

    const long long aTile = (long long)rb * 32768;
    const long long wTile = (long long)cb * 32768;

    i32x16 acc[6];
#pragma unroll
    for (int g = 0; g < 6; ++g)
#pragma unroll
        for (int r = 0; r < 16; ++r) acc[g][r] = 0;

    // fragment read offsets (K-major, conflict-free)
    const int roA = (l >> 5) * 1024 + (32 * wr + (l & 31)) * 16;
    const int roW = (l >> 5) * 1024 + (32 * wc + (l & 31)) * 16;

    char* smb = &sm[0][0];
    if (w < 2) {
        Stager<6> st;
        st.init(6 * w, Asl, Wsl, aTile, wTile, l);
        st.issue(smb);            // batch 0 -> buf0
        st.issue(smb + CH8);      // batch 1 -> buf1
        asm volatile("s_waitcnt vmcnt(6)" ::: "memory");   // batch 0 done
        __builtin_amdgcn_sched_barrier(0);
        asm volatile("s_barrier" ::: "memory");
        __builtin_amdgcn_sched_barrier(0);
        gemm8_loop<6>(st, smb, acc, roA, roW);
    } else {
        Stager<5> st;
        st.init(12 + 5 * (w - 2), Asl, Wsl, aTile, wTile, l);
        st.issue(smb);
        st.issue(smb + CH8);
        asm volatile("s_waitcnt vmcnt(5)" ::: "memory");
        __builtin_amdgcn_sched_barrier(0);
        asm volatile("s_barrier" ::: "memory");
        __builtin_amdgcn_sched_barrier(0);
        gemm8_loop<5>(st, smb, acc, roA, roW);
    }

    // ---- combine groups -> f64 h, store hbuf, fused channel sums ----
    int irw[16];
#pragma unroll
    for (int r = 0; r < 16; ++r) irw[r] = (int)irow8[l * 16 + r];
    const int icl = (int)icol8[l];

    const double C7 = 1.0 / 128.0, CMB = 1.0 / 1024.0;
    double lsum = 0.0, lsq = 0.0;
    const int colg = cb * 64 + 32 * wc + icl;
    const int row0 = rb * 64 + 32 * wr;
#pragma unroll
    for (int r = 0; r < 16; ++r) {
        double t = (double)acc[5][r];
        t = fma(t, C7, (double)acc[4][r]);
        t = fma(t, C7, (double)acc[3][r]);
        t = fma(t, C7, (double)acc[2][r]);
        t = fma(t, C7, (double)acc[1][r]);
        t = fma(t, C7, (double)acc[0][r]);
        const double h = t * CMB;
        hbuf[(size_t)(row0 + irw[r]) * DDIM + colg] = h;
        lsum += h;
        lsq = fma(h, h, lsq);
    }

    __syncthreads();                       // LDS -> scratch reuse
    double* Ss = (double*)sm;              // [64 cols][4 ctr] sum, then sq
    const int ctr = wr * 2 + (l >> 5);
    const int cloc = 32 * wc + icl;
    Ss[cloc * 4 + ctr] = lsum;
    Ss[256 + cloc * 4 + ctr] = lsq;
    __syncthreads();
    if (tid < 64) {
        double s = 0.0, q = 0.0;
#pragma unroll
        for (int k = 0; k < 4; ++k) {
            s += Ss[tid * 4 + k];
            q += Ss[256 + tid * 4 + k];
        }
        atomicAdd(&sums[cb * 64 + tid], s);
        atomicAdd(&sums[512 + cb * 64 + tid], q);
    }
}

// ========== f64 MFMA GEMM (R6, proven fallback for mid-size ws) ==========
__global__ __launch_bounds__(256, 2)
void gemm3_k(const float* __restrict__ mx, const float* __restrict__ Wm,
             double* __restrict__ hbuf, double* __restrict__ sums,
             const double* __restrict__ rowmap)
{
    __shared__ double Atr[BK3 * AP3];
    __shared__ double Wt [BK3 * WP3];

    const int tid = threadIdx.x;
    const int bid = blockIdx.x;
    const int rb  = ((bid >> 6) << 3) | (bid & 7);
    const int cb  = (bid >> 3) & 7;
    const int row0 = rb * BM3;
    const int col0 = cb * BN3;

    const int w  = tid >> 6;
    const int l  = tid & 63;
    const int wr = w >> 1;
    const int wc = w & 1;
    const int lr = l & 15;
    const int kq = l >> 4;

    int irow[4];
#pragma unroll
    for (int r = 0; r < 4; ++r)
        irow[r] = (int)rowmap[l * 4 + r];

    const int arow = tid >> 1;
    const int af   = (tid & 1) * 8;
    const int wrow = tid >> 2;
    const int wf   = (tid & 3) * 4;
    const float* aSrc = mx + (size_t)(row0 + arow) * DDIM + af;
    const float* wSrc = Wm + (size_t)(col0 + wrow) * DDIM + wf;

    d4 acc[4][2];
#pragma unroll
    for (int i = 0; i < 4; ++i)
#pragma unroll
        for (int j = 0; j < 2; ++j) acc[i][j] = (d4){0.0, 0.0, 0.0, 0.0};

    float4 pa0 = *(const float4*)(aSrc + 0);
    float4 pa1 = *(const float4*)(aSrc + 4);
    float4 pw  = *(const float4*)(wSrc + 0);

    for (int kk = 0; kk < DDIM; kk += BK3) {
        __syncthreads();
        Atr[(af + 0) * AP3 + arow] = (double)pa0.x;
        Atr[(af + 1) * AP3 + arow] = (double)pa0.y;
        Atr[(af + 2) * AP3 + arow] = (double)pa0.z;
        Atr[(af + 3) * AP3 + arow] = (double)pa0.w;
        Atr[(af + 4) * AP3 + arow] = (double)pa1.x;
        Atr[(af + 5) * AP3 + arow] = (double)pa1.y;
        Atr[(af + 6) * AP3 + arow] = (double)pa1.z;
        Atr[(af + 7) * AP3 + arow] = (double)pa1.w;
        Wt[(wf + 0) * WP3 + wrow] = (double)pw.x;
        Wt[(wf + 1) * WP3 + wrow] = (double)pw.y;
        Wt[(wf + 2) * WP3 + wrow] = (double)pw.z;
        Wt[(wf + 3) * WP3 + wrow] = (double)pw.w;
        __syncthreads();

        if (kk + BK3 < DDIM) {
            pa0 = *(const float4*)(aSrc + kk + BK3 + 0);
            pa1 = *(const float4*)(aSrc + kk + BK3 + 4);
            pw  = *(const float4*)(wSrc + kk + BK3 + 0);
        }

#pragma unroll
        for (int ks = 0; ks < BK3 / 4; ++ks) {
            const int kabs = ks * 4 + kq;
            double a[4], b[2];
#pragma unroll
            for (int i = 0; i < 4; ++i)
                a[i] = Atr[kabs * AP3 + 64 * wr + 16 * i + lr];
#pragma unroll
            for (int j = 0; j < 2; ++j)
                b[j] = Wt[kabs * WP3 + 32 * wc + 16 * j + lr];
#pragma unroll
            for (int i = 0; i < 4; ++i)
#pragma unroll
                for (int j = 0; j < 2; ++j)
                    acc[i][j] = __builtin_amdgcn_mfma_f64_16x16x4f64(
                                    a[i], b[j], acc[i][j], 0, 0, 0);
        }
    }

#pragma unroll
    for (int i = 0; i < 4; ++i) {
#pragma unroll
        for (int j = 0; j < 2; ++j) {
            const size_t cbase = (size_t)col0 + 32 * wc + 16 * j + lr;
            const size_t rbase = (size_t)row0 + 64 * wr + 16 * i;
#pragma unroll
            for (int r = 0; r < 4; ++r)
                hbuf[(rbase + irow[r]) * DDIM + cbase] = acc[i][j][r];
        }
    }

    __syncthreads();
    double* Ssum = Atr;
    double* Ssq  = Atr + 512;
    const int ctr = wr * 4 + kq;
#pragma unroll
    for (int j = 0; j < 2; ++j) {
        const int cloc = 32 * wc + 16 * j + lr;
        double s = 0.0, q = 0.0;
#pragma unroll
        for (int i = 0; i < 4; ++i)
#pragma unroll
            for (int r = 0; r < 4; ++r) {
                const double v = acc[i][j][r];
                s += v;
                q = fma(v, v, q);
            }
        Ssum[cloc * 8 + ctr] = s;
        Ssq [cloc * 8 + ctr] = q;
    }
    __syncthreads();
    if (tid < 64) {
        double s = 0.0, q = 0.0;
#pragma unroll
        for (int c = 0; c < 8; ++c) {
            s += Ssum[tid * 8 + c];
            q += Ssq [tid * 8 + c];
        }
        atomicAdd(&sums[col0 + tid], s);
        atomicAdd(&sums[512 + col0 + tid], q);
    }
}

// ============ fallback small-ws kernel ============
template<int MODE>
__global__ __launch_bounds__(256)
void gemm_k(const float* __restrict__ mx, const float* __restrict__ Wm,
            double* __restrict__ hbuf, double* __restrict__ sums,
            const double* __restrict__ scale, const double* __restrict__ shiftv,
            const float* __restrict__ x, float* __restrict__ out)
{
    __shared__ __align__(16) char smem[LDS_BYTES];
    double (*Ald)[APITCH] = reinterpret_cast<double(*)[APITCH]>(smem);
    double (*Wld)[WPITCH] = reinterpret_cast<double(*)[WPITCH]>(smem + (size_t)BM * APITCH * 8);

    const int tid  = threadIdx.x;
    const int rb   = blockIdx.x >> 2;
    const int cb   = blockIdx.x & 3;
    const int row0 = rb * BM;
    const int col0 = cb * BNT;

    const int arow = tid >> 2;
    const int ak   = (tid & 3) * 8;
    const int erow = tid >> 1;
    const int wk   = (tid & 1) * 16;

    const float* aSrc = mx + (size_t)(row0 + arow) * DDIM;
    const float* wSrc = Wm + (size_t)(col0 + erow) * DDIM;

    const int rg = tid >> 4;
    const int cg = tid & 15;

    double acc[4][8];
#pragma unroll
    for (int i = 0; i < 4; ++i)
#pragma unroll
        for (int j = 0; j < 8; ++j) acc[i][j] = 0.0;

    for (int kk = 0; kk < DDIM; kk += BK) {
        const float4 a0 = *(const float4*)(aSrc + kk + ak);
        const float4 a1 = *(const float4*)(aSrc + kk + ak + 4);
        const float4 w0 = *(const float4*)(wSrc + kk + wk);
        const float4 w1 = *(const float4*)(wSrc + kk + wk + 4);
        const float4 w2 = *(const float4*)(wSrc + kk + wk + 8);
        const float4 w3 = *(const float4*)(wSrc + kk + wk + 12);
        __syncthreads();
        Ald[arow][ak + 0] = (double)a0.x; Ald[arow][ak + 1] = (double)a0.y;
        Ald[arow][ak + 2] = (double)a0.z; Ald[arow][ak + 3] = (double)a0.w;
        Ald[arow][ak + 4] = (double)a1.x; Ald[arow][ak + 5] = (double)a1.y;
        Ald[arow][ak + 6] = (double)a1.z; Ald[arow][ak + 7] = (double)a1.w;
        const float wfv[16] = {w0.x, w0.y, w0.z, w0.w, w1.x, w1.y, w1.z, w1.w,
                               w2.x, w2.y, w2.z, w2.w, w3.x, w3.y, w3.z, w3.w};
#pragma unroll
        for (int q = 0; q < 16; ++q) Wld[wk + q][erow] = (double)wfv[q];
        __syncthreads();

#pragma unroll 4
        for (int d = 0; d < BK; ++d) {
            double a[4], wv[8];
#pragma unroll
            for (int i = 0; i < 4; ++i) a[i] = Ald[rg * 4 + i][d];
#pragma unroll
            for (int j = 0; j < 8; ++j) wv[j] = Wld[d][cg * 8 + j];
#pragma unroll
            for (int i = 0; i < 4; ++i)
#pragma unroll
                for (int j = 0; j < 8; ++j)
                    acc[i][j] = fma(a[i], wv[j], acc[i][j]);
        }
    }

    if (MODE <= 1) {
        __syncthreads();
        double* scr = reinterpret_cast<double*>(smem);
#pragma unroll
        for (int j = 0; j < 8; ++j) {
            const double s = acc[0][j] + acc[1][j] + acc[2][j] + acc[3][j];
            const double q = acc[0][j]*acc[0][j] + acc[1][j]*acc[1][j]
                           + acc[2][j]*acc[2][j] + acc[3][j]*acc[3][j];
            scr[(cg * 8 + j) * 16 + rg] = s;
            scr[2048 + (cg * 8 + j) * 16 + rg] = q;
        }
        __syncthreads();
        if (tid < 128) {
            double s = 0.0, q = 0.0;
#pragma unroll
            for (int r = 0; r < 16; ++r) {
                s += scr[tid * 16 + r];
                q += scr[2048 + tid * 16 + r];
            }
            atomicAdd(&sums[col0 + tid], s);
            atomicAdd(&sums[512 + col0 + tid], q);
        }
    }

    if (MODE == 2) {
        const int p  = rb * 16 + rg;
        const int nn = p >> 6;
        const int bb = p & 63;
#pragma unroll
        for (int j = 0; j < 8; ++j) {
            const int e = col0 + cg * 8 + j;
            const double sc = scale[e];
            const double sh = shiftv[e];
            const size_t basex = (size_t)bb * (NDIM * DDIM) + (size_t)nn * DDIM + e;
            double v = 0.0;
#pragma unroll
            for (int t = 0; t < 4; ++t) {
                const double hn = fma(acc[t][j], sc, sh);
                v = v + (hn - v) / 2.0;
                const bool s = (v - 0.5) >= 0.0;
                const size_t xi = (size_t)t * BND + basex;
                out[xi] = s ? x[xi] : 0.0f;
                if (s) v = 0.0;
            }
        }
    }
}

__global__ void zero_k(double* sums)
{
    const int i = blockIdx.x * 256 + threadIdx.x;
    if (i < 1024) sums[i] = 0.0;
}

__global__ void stat_k(const double* __restrict__ sums,
                       const float* __restrict__ gamma, const float* __restrict__ beta,
                       double* __restrict__ scale, double* __restrict__ shiftv)
{
    const int e = blockIdx.x * 256 + threadIdx.x;
    if (e < 512) {
        const double mean = sums[e] * (1.0 / 65536.0);
        const double msq  = sums[512 + e] * (1.0 / 65536.0);
        const double var  = msq - mean * mean;
        const double inv  = 1.0 / sqrt(var + BN_EPS);
        const double g    = (double)gamma[e] * inv;
        scale[e]  = g;
        shiftv[e] = (double)beta[e] - mean * g;
    }
}

// LIF pass, 2 channels per thread (double2/float2 vectorized)
__global__ __launch_bounds__(256)
void lifh_k(const double* __restrict__ hbuf, const double* __restrict__ scale,
            const double* __restrict__ shiftv, const float* __restrict__ x,
            float* __restrict__ out)
{
    const size_t i = (size_t)blockIdx.x * 256 + threadIdx.x;   // < B*N*D/2
    const int e2 = (int)(i & 255) * 2;
    const size_t p = i >> 8;            // p = n*B + b
    const int nn = (int)(p >> 6);
    const int bb = (int)(p & 63);
    const double2 sc = *(const double2*)&scale[e2];
    const double2 sh = *(const double2*)&shiftv[e2];
    const double* hp = hbuf + p * 2048 + e2;
    const size_t basex = (size_t)bb * (NDIM * DDIM) + (size_t)nn * DDIM + e2;
    double v0 = 0.0, v1 = 0.0;
#pragma unroll
    for (int t = 0; t < 4; ++t) {
        const double2 h2 = *(const double2*)(hp + (size_t)t * 512);
        const double hn0 = fma(h2.x, sc.x, sh.x);
        const double hn1 = fma(h2.y, sc.y, sh.y);
        v0 = v0 + (hn0 - v0) / 2.0;
        v1 = v1 + (hn1 - v1) / 2.0;
        const bool s0 = (v0 - 0.5) >= 0.0;
        const bool s1 = (v1 - 0.5) >= 0.0;
        const size_t xi = (size_t)t * BND + basex;
        const float2 xv = *(const float2*)(x + xi);
        float2 ov;
        ov.x = s0 ? xv.x : 0.0f;
        ov.y = s1 ? xv.y : 0.0f;
        *(float2*)(out + xi) = ov;
        if (s0) v0 = 0.0;
        if (s1) v1 = 0.0;
    }
}

extern "C" void kernel_launch(void* const* d_in, const int* in_sizes, int n_in,
                              void* d_out, int out_size, void* d_ws, size_t ws_size,
                              hipStream_t stream)
{
    const float* x     = (const float*)d_in[0];
    const float* mx    = (const float*)d_in[1];
    const float* Wm    = (const float*)d_in[2];
    const float* gamma = (const float*)d_in[3];
    const float* beta  = (const float*)d_in[4];
    float* out = (float*)d_out;

    char* ws = (char*)d_ws;
    double* sums   = (double*)ws;             // [1024]
    double* scale  = (double*)(ws + 8192);    // [512]
    double* shiftv = scale + 512;             // [512]
    double* rowmap = (double*)(ws + 16384);   // [256]  (f64 path)
    double* irow8  = (double*)(ws + 18432);   // [1024] (i8 path)
    double* icol8  = (double*)(ws + 26624);   // [64]
    double* hbuf   = (double*)(ws + 32768);   // [65536*512] f64

    const size_t HBSZ   = (size_t)MROWS * DDIM * 8;          // 268435456
    const size_t OFF_AS = 32768 + HBSZ;                      // A slices
    const size_t ASSZ   = (size_t)NSA * APL;                 // 201326592
    const size_t OFF_WS = OFF_AS + ASSZ;
    const size_t WSSZ   = (size_t)NSW * WPL;                 // 1310720
    const size_t need8  = OFF_WS + WSSZ;                     // ~471.1 MB
    const size_t need_h = 32768 + HBSZ;                      // ~268.5 MB

    hipLaunchKernelGGL(zero_k, dim3(4), dim3(256), 0, stream, sums);

    if (ws_size >= need8) {
        char* Asl = ws + OFF_AS;
        char* Wsl = ws + OFF_WS;
        hipLaunchKernelGGL(probe8_k, dim3(1), dim3(64), 0, stream, irow8, icol8);
        hipLaunchKernelGGL(slice_a_k, dim3(1024), dim3(256), 0, stream, mx, Asl);
        hipLaunchKernelGGL(slice_w_k, dim3(64), dim3(256), 0, stream, Wm, Wsl);
        hipLaunchKernelGGL(gemm8_k, dim3(8192), dim3(256), 0, stream,
                           Asl, Wsl, hbuf, sums, irow8, icol8);
        hipLaunchKernelGGL(stat_k, dim3(2), dim3(256), 0, stream,
                           sums, gamma, beta, scale, shiftv);
        hipLaunchKernelGGL(lifh_k, dim3(16384), dim3(256), 0, stream,
                           hbuf, scale, shiftv, x, out);
    } else if (ws_size >= need_h) {
        hipLaunchKernelGGL(probe_k, dim3(1), dim3(64), 0, stream, rowmap);
        hipLaunchKernelGGL(gemm3_k, dim3(4096), dim3(256), 0, stream,
                           mx, Wm, hbuf, sums, rowmap);
        hipLaunchKernelGGL(stat_k, dim3(2), dim3(256), 0, stream,
                           sums, gamma, beta, scale, shiftv);
        hipLaunchKernelGGL(lifh_k, dim3(16384), dim3(256), 0, stream,
                           hbuf, scale, shiftv, x, out);
    } else {
        hipLaunchKernelGGL((gemm_k<0>), dim3(4096), dim3(256), 0, stream,
                           mx, Wm, nullptr, sums, nullptr, nullptr, nullptr, nullptr);
        hipLaunchKernelGGL(stat_k, dim3(2), dim3(256), 0, stream,
                           sums, gamma, beta, scale, shiftv);
        hipLaunchKernelGGL((gemm_k<2>), dim3(4096), dim3(256), 0, stream,
                           mx, Wm, nullptr, nullptr, scale, shiftv, x, out);
    }
}

// Round 11
// 472.933 us; speedup vs baseline: 1.0792x; 1.0792x over previous
//
#include <hip/hip_runtime.h>
#include <math.h>

// Problem dims (fixed): T=4, B=64, N=256, D=512.
// GEMM rows r = (n*B+b)*T + t == natural row order of mx [N,B,T,D] -> A = mx.
namespace {
constexpr int TDIM = 4, BDIM = 64, NDIM = 256, DDIM = 512;
constexpr int MROWS = 65536;               // N*B*T
constexpr long long BND = 8388608LL;       // B*N*D
constexpr double BN_EPS = 1e-5;

// ---- fallback tiling (small-ws path) ----
constexpr int BM = 64, BNT = 128, BK = 32;
constexpr int APITCH = BK + 2;
constexpr int WPITCH = BNT + 4;
constexpr int LDS_BYTES = (BM * APITCH + BK * WPITCH) * 8;

// ---- f64-MFMA path (R6, proven): 128x64 block, 4 waves of 64x32, BK=16 ----
constexpr int BM3 = 128, BN3 = 64, BK3 = 16;
constexpr int AP3 = BM3 + 1;
constexpr int WP3 = BN3 + 1;

// ---- i8-Ozaki path ----
// A sliced (scale 4) into 6 radix-128 digits; W (scale 256) into 5.
// h = 2^-10 * sum_{g<=5} 128^-g * G_g, G_g = sum_{s+t=g} A_s.W_t (i32-exact).
// Slice planes stored BLOCKED K-MAJOR: plane + tile*32768 + kseg*1024 + ri*16.
constexpr int NSA = 6, NSW = 5;
constexpr long long APL = 33554432LL;      // A plane bytes: 65536*512
constexpr long long WPL = 262144LL;        // W plane bytes: 512*512
constexpr int CH8 = 22528;                 // LDS per buffer: A 6*2048 + W 5*2048
}

typedef double d4 __attribute__((ext_vector_type(4)));
typedef int i32x4 __attribute__((ext_vector_type(4)));
typedef int i32x16 __attribute__((ext_vector_type(16)));

#define GLOAD16(g, d) __builtin_amdgcn_global_load_lds( \
    (const __attribute__((address_space(1))) void*)(g), \
    (__attribute__((address_space(3))) void*)(d), 16, 0, 0)

// ======= probe: D row mapping of v_mfma_f64_16x16x4f64 (f64 path) =======
__global__ void probe_k(double* __restrict__ rowmap)
{
    const int l = threadIdx.x;
    d4 z = {0.0, 0.0, 0.0, 0.0};
    d4 dr = __builtin_amdgcn_mfma_f64_16x16x4f64((double)(l & 15), 1.0, z, 0, 0, 0);
#pragma unroll
    for (int r = 0; r < 4; ++r)
        rowmap[l * 4 + r] = dr[r] * 0.25;
}

// ======= probe: D row/col mapping of v_mfma_i32_32x32x32_i8 =======
__global__ void probe8_k(double* __restrict__ irow8, double* __restrict__ icol8)
{
    const int l = threadIdx.x;      // 64 threads = 1 wave
    i32x16 z;
#pragma unroll
    for (int r = 0; r < 16; ++r) z[r] = 0;
    const int mb = (l & 31) * 0x01010101;
    const int ob = 0x01010101;
    i32x4 am = {mb, mb, mb, mb};
    i32x4 a1 = {ob, ob, ob, ob};
    i32x16 d1 = __builtin_amdgcn_mfma_i32_32x32x32_i8(am, a1, z, 0, 0, 0);
#pragma unroll
    for (int r = 0; r < 16; ++r)
        irow8[l * 16 + r] = (double)d1[r] / 32.0;
    i32x16 d2 = __builtin_amdgcn_mfma_i32_32x32x32_i8(a1, am, z, 0, 0, 0);
    icol8[l] = (double)d2[0] / 32.0;
}

// ======= A slicing -> blocked K-major planes =======
// digit0 in f64; residual V-rint(V) has <=24 significand bits -> exact f32 path.
__global__ __launch_bounds__(256)
void slice_a_k(const float* __restrict__ src, char* __restrict__ dst)
{
    const int ri  = threadIdx.x & 63;
    const int ks0 = threadIdx.x >> 6;          // 0..3
    const long long row = (long long)blockIdx.x * 64 + ri;
#pragma unroll 1
    for (int it = 0; it < 8; ++it) {
        const int kseg = it * 4 + ks0;         // 0..31
        const float* sp = src + row * DDIM + kseg * 16;
        union { char c[16]; i32x4 v; } pk[NSA];
#pragma unroll
        for (int e = 0; e < 16; ++e) {
            const double V = (double)sp[e] * 4.0;
            const double u = rint(V);
            pk[0].c[e] = (char)(int)u;
            float r = (float)(V - u);          // exact
#pragma unroll
            for (int s = 1; s < NSA; ++s) {
                r *= 128.0f;                   // exact (pow2)
                const float uf = rintf(r);
                r -= uf;                       // exact
                pk[s].c[e] = (char)(int)uf;
            }
        }
        const long long base = (long long)blockIdx.x * 32768 + kseg * 1024 + ri * 16;
#pragma unroll
        for (int s = 0; s < NSA; ++s)
            *(i32x4*)(dst + (long long)s * APL + base) = pk[s].v;
    }
}

// ======= W slicing -> blocked K-major planes (8 col tiles) =======
__global__ __launch_bounds__(256)
void slice_w_k(const float* __restrict__ src, char* __restrict__ dst)
{
    const int cbk  = blockIdx.x >> 3;          // 0..7 col tile
    const int kgrp = blockIdx.x & 7;
    const int ci   = threadIdx.x & 63;
    const int kseg = kgrp * 4 + (threadIdx.x >> 6);   // 0..31
    const float* sp = src + (long long)(cbk * 64 + ci) * DDIM + kseg * 16;
    union { char c[16]; i32x4 v; } pk[NSW];
#pragma unroll
    for (int e = 0; e < 16; ++e) {
        const double V = (double)sp[e] * 256.0;
        const double u = rint(V);
        pk[0].c[e] = (char)(int)u;
        float r = (float)(V - u);              // exact
#pragma unroll
        for (int s = 1; s < NSW; ++s) {
            r *= 128.0f;
            const float uf = rintf(r);
            r -= uf;
            pk[s].c[e] = (char)(int)uf;
        }
    }
    const long long base = (long long)cbk * 32768 + kseg * 1024 + ci * 16;
#pragma unroll
    for (int s = 0; s < NSW; ++s)
        *(i32x4*)(dst + (long long)s * WPL + base) = pk[s].v;
}

// ======= per-wave staging: NW windows, chunk-indexed base pointers =======
template<int NW>
struct Stager {
    const char* gb[NW];     // chunk-0 global pointers
    int lo[NW];             // LDS offsets within buffer
    __device__ __forceinline__ void init(int w0, const char* Asl, const char* Wsl,
                                         long long aT, long long wT, int l)
    {
#pragma unroll
        for (int i = 0; i < NW; ++i) {
            const int idx = w0 + i;
            if (idx < 12) {
                gb[i] = Asl + (long long)(idx >> 1) * APL + aT
                      + (long long)(idx & 1) * 1024 + l * 16;
                lo[i] = (idx >> 1) * 2048 + (idx & 1) * 1024;
            } else {
                const int e = idx - 12;
                gb[i] = Wsl + (long long)(e >> 1) * WPL + wT
                      + (long long)(e & 1) * 1024 + l * 16;
                lo[i] = 12288 + (e >> 1) * 2048 + (e & 1) * 1024;
            }
        }
    }
    __device__ __forceinline__ void issue(char* buf, int ck)
    {
        const int go = ck * 2048;
#pragma unroll
        for (int i = 0; i < NW; ++i)
            GLOAD16(gb[i] + go, buf + lo[i]);
    }
};

// ======= main K-loop: counted vmcnt, raw barriers (T3/T4), chunk rotation =======
// Chunk order (c0, c0+1, ..., mod 16) is per-block; exact int accumulation makes
// order irrelevant to the result. De-phases co-resident blocks on a CU.
template<int NW>
__device__ __forceinline__ void gemm8_loop(Stager<NW>& st, char* smb,
                                           i32x16 (&acc)[6], int roA, int roW,
                                           int c0)
{
#pragma unroll 2
    for (int c = 0; c < 16; ++c) {
        const char* bA = smb + (c & 1) * CH8;
        const char* bW = bA + 12288;
        i32x4 af[NSA], wf[NSW];
#pragma unroll
        for (int s = 0; s < NSA; ++s)
            af[s] = *(const i32x4*)(bA + s * 2048 + roA);
#pragma unroll
        for (int t = 0; t < NSW; ++t)
            wf[t] = *(const i32x4*)(bW + t * 2048 + roW);
#pragma unroll
        for (int s = 0; s < NSA; ++s)
#pragma unroll
            for (int t = 0; t < NSW; ++t)
                if (s + t <= 5)
                    acc[s + t] = __builtin_amdgcn_mfma_i32_32x32x32_i8(
                                     af[s], wf[t], acc[s + t], 0, 0, 0);
        if (c == 15) break;
        // all waves done reading buf[c&1] (ds_reads consumed by MFMA issue)
        asm volatile("s_barrier" ::: "memory");
        if (c < 14) {
            st.issue(smb + (c & 1) * CH8, (c0 + c + 2) & 15);   // chunk c+2
            if constexpr (NW == 6)
                asm volatile("s_waitcnt vmcnt(6)" ::: "memory");  // chunk c+1 done
            else
                asm volatile("s_waitcnt vmcnt(5)" ::: "memory");
        } else {
            asm volatile("s_waitcnt vmcnt(0)" ::: "memory");      // tail drain
        }
        __builtin_amdgcn_sched_barrier(0);
        asm volatile("s_barrier" ::: "memory");   // chunk c+1 visible to all
        __builtin_amdgcn_sched_barrier(0);
    }
}

// ======= i8-Ozaki exact GEMM: 64x64 block, 4 waves of 32x32 =======
__global__ __launch_bounds__(256, 3)
void gemm8_k(const char* __restrict__ Asl, const char* __restrict__ Wsl,
             double* __restrict__ hbuf, double* __restrict__ sums,
             const double* __restrict__ irow8, const double* __restrict__ icol8)
{
    __shared__ __align__(16) char sm[2][CH8];

    const int tid = threadIdx.x;
    // XCD swizzle: 8 col-blocks of one row-block land on one XCD.
    const int bid = blockIdx.x;                     // 0..8191
    const int rb  = ((bid >> 6) << 3) | (bid & 7);  // 0..1023
    const int cb  = (bid >> 3) & 7;                 // 0..7

    // chunk-phase: same for siblings of a row-block (A-tile L2 locality kept),
    // different for co-resident blocks from different row-groups (de-phased).
    const int c0 = (((bid >> 6) * 5) + ((bid & 7) * 3)) & 15;

    const int w  = tid >> 6;       // wave 0..3
    const int l  = tid & 63;
    const int wr = w >> 1;         // row slab (0..1) -> 32 rows
    const int wc = w & 1;          // col slab (0..1) -> 32 cols

    const long long aTile = (long long)rb * 32768;
    const long long wTile = (long long)cb * 32768;

    i32x16 acc[6];
#pragma unroll
    for (int g = 0; g < 6; ++g)
#pragma unroll
        for (int r = 0; r < 16; ++r) acc[g][r] = 0;

    // fragment read offsets (K-major, conflict-free)
    const int roA = (l >> 5) * 1024 + (32 * wr + (l & 31)) * 16;
    const int roW = (l >> 5) * 1024 + (32 * wc + (l & 31)) * 16;

    char* smb = &sm[0][0];
    if (w < 2) {
        Stager<6> st;
        st.init(6 * w, Asl, Wsl, aTile, wTile, l);
        st.issue(smb, c0);                  // chunk c0 -> buf0
        st.issue(smb + CH8, (c0 + 1) & 15); // chunk c0+1 -> buf1
        asm volatile("s_waitcnt vmcnt(6)" ::: "memory");   // chunk c0 done
        __builtin_amdgcn_sched_barrier(0);
        asm volatile("s_barrier" ::: "memory");
        __builtin_amdgcn_sched_barrier(0);
        gemm8_loop<6>(st, smb, acc, roA, roW, c0);
    } else {
        Stager<5> st;
        st.init(12 + 5 * (w - 2), Asl, Wsl, aTile, wTile, l);
        st.issue(smb, c0);
        st.issue(smb + CH8, (c0 + 1) & 15);
        asm volatile("s_waitcnt vmcnt(5)" ::: "memory");
        __builtin_amdgcn_sched_barrier(0);
        asm volatile("s_barrier" ::: "memory");
        __builtin_amdgcn_sched_barrier(0);
        gemm8_loop<5>(st, smb, acc, roA, roW, c0);
    }

    // ---- combine groups -> f64 h, store hbuf, fused channel sums ----
    int irw[16];
#pragma unroll
    for (int r = 0; r < 16; ++r) irw[r] = (int)irow8[l * 16 + r];
    const int icl = (int)icol8[l];

    const double C7 = 1.0 / 128.0, CMB = 1.0 / 1024.0;
    double lsum = 0.0, lsq = 0.0;
    const int colg = cb * 64 + 32 * wc + icl;
    const int row0 = rb * 64 + 32 * wr;
#pragma unroll
    for (int r = 0; r < 16; ++r) {
        double t = (double)acc[5][r];
        t = fma(t, C7, (double)acc[4][r]);
        t = fma(t, C7, (double)acc[3][r]);
        t = fma(t, C7, (double)acc[2][r]);
        t = fma(t, C7, (double)acc[1][r]);
        t = fma(t, C7, (double)acc[0][r]);
        const double h = t * CMB;
        hbuf[(size_t)(row0 + irw[r]) * DDIM + colg] = h;
        lsum += h;
        lsq = fma(h, h, lsq);
    }

    __syncthreads();                       // LDS -> scratch reuse
    double* Ss = (double*)sm;              // [64 cols][4 ctr] sum, then sq
    const int ctr = wr * 2 + (l >> 5);
    const int cloc = 32 * wc + icl;
    Ss[cloc * 4 + ctr] = lsum;
    Ss[256 + cloc * 4 + ctr] = lsq;
    __syncthreads();
    if (tid < 64) {
        double s = 0.0, q = 0.0;
#pragma unroll
        for (int k = 0; k < 4; ++k) {
            s += Ss[tid * 4 + k];
            q += Ss[256 + tid * 4 + k];
        }
        atomicAdd(&sums[cb * 64 + tid], s);
        atomicAdd(&sums[512 + cb * 64 + tid], q);
    }
}

// ========== f64 MFMA GEMM (R6, proven fallback for mid-size ws) ==========
__global__ __launch_bounds__(256, 2)
void gemm3_k(const float* __restrict__ mx, const float* __restrict__ Wm,
             double* __restrict__ hbuf, double* __restrict__ sums,
             const double* __restrict__ rowmap)
{
    __shared__ double Atr[BK3 * AP3];
    __shared__ double Wt [BK3 * WP3];

    const int tid = threadIdx.x;
    const int bid = blockIdx.x;
    const int rb  = ((bid >> 6) << 3) | (bid & 7);
    const int cb  = (bid >> 3) & 7;
    const int row0 = rb * BM3;
    const int col0 = cb * BN3;

    const int w  = tid >> 6;
    const int l  = tid & 63;
    const int wr = w >> 1;
    const int wc = w & 1;
    const int lr = l & 15;
    const int kq = l >> 4;

    int irow[4];
#pragma unroll
    for (int r = 0; r < 4; ++r)
        irow[r] = (int)rowmap[l * 4 + r];

    const int arow = tid >> 1;
    const int af   = (tid & 1) * 8;
    const int wrow = tid >> 2;
    const int wf   = (tid & 3) * 4;
    const float* aSrc = mx + (size_t)(row0 + arow) * DDIM + af;
    const float* wSrc = Wm + (size_t)(col0 + wrow) * DDIM + wf;

    d4 acc[4][2];
#pragma unroll
    for (int i = 0; i < 4; ++i)
#pragma unroll
        for (int j = 0; j < 2; ++j) acc[i][j] = (d4){0.0, 0.0, 0.0, 0.0};

    float4 pa0 = *(const float4*)(aSrc + 0);
    float4 pa1 = *(const float4*)(aSrc + 4);
    float4 pw  = *(const float4*)(wSrc + 0);

    for (int kk = 0; kk < DDIM; kk += BK3) {
        __syncthreads();
        Atr[(af + 0) * AP3 + arow] = (double)pa0.x;
        Atr[(af + 1) * AP3 + arow] = (double)pa0.y;
        Atr[(af + 2) * AP3 + arow] = (double)pa0.z;
        Atr[(af + 3) * AP3 + arow] = (double)pa0.w;
        Atr[(af + 4) * AP3 + arow] = (double)pa1.x;
        Atr[(af + 5) * AP3 + arow] = (double)pa1.y;
        Atr[(af + 6) * AP3 + arow] = (double)pa1.z;
        Atr[(af + 7) * AP3 + arow] = (double)pa1.w;
        Wt[(wf + 0) * WP3 + wrow] = (double)pw.x;
        Wt[(wf + 1) * WP3 + wrow] = (double)pw.y;
        Wt[(wf + 2) * WP3 + wrow] = (double)pw.z;
        Wt[(wf + 3) * WP3 + wrow] = (double)pw.w;
        __syncthreads();

        if (kk + BK3 < DDIM) {
            pa0 = *(const float4*)(aSrc + kk + BK3 + 0);
            pa1 = *(const float4*)(aSrc + kk + BK3 + 4);
            pw  = *(const float4*)(wSrc + kk + BK3 + 0);
        }

#pragma unroll
        for (int ks = 0; ks < BK3 / 4; ++ks) {
            const int kabs = ks * 4 + kq;
            double a[4], b[2];
#pragma unroll
            for (int i = 0; i < 4; ++i)
                a[i] = Atr[kabs * AP3 + 64 * wr + 16 * i + lr];
#pragma unroll
            for (int j = 0; j < 2; ++j)
                b[j] = Wt[kabs * WP3 + 32 * wc + 16 * j + lr];
#pragma unroll
            for (int i = 0; i < 4; ++i)
#pragma unroll
                for (int j = 0; j < 2; ++j)
                    acc[i][j] = __builtin_amdgcn_mfma_f64_16x16x4f64(
                                    a[i], b[j], acc[i][j], 0, 0, 0);
        }
    }

#pragma unroll
    for (int i = 0; i < 4; ++i) {
#pragma unroll
        for (int j = 0; j < 2; ++j) {
            const size_t cbase = (size_t)col0 + 32 * wc + 16 * j + lr;
            const size_t rbase = (size_t)row0 + 64 * wr + 16 * i;
#pragma unroll
            for (int r = 0; r < 4; ++r)
                hbuf[(rbase + irow[r]) * DDIM + cbase] = acc[i][j][r];
        }
    }

    __syncthreads();
    double* Ssum = Atr;
    double* Ssq  = Atr + 512;
    const int ctr = wr * 4 + kq;
#pragma unroll
    for (int j = 0; j < 2; ++j) {
        const int cloc = 32 * wc + 16 * j + lr;
        double s = 0.0, q = 0.0;
#pragma unroll
        for (int i = 0; i < 4; ++i)
#pragma unroll
            for (int r = 0; r < 4; ++r) {
                const double v = acc[i][j][r];
                s += v;
                q = fma(v, v, q);
            }
        Ssum[cloc * 8 + ctr] = s;
        Ssq [cloc * 8 + ctr] = q;
    }
    __syncthreads();
    if (tid < 64) {
        double s = 0.0, q = 0.0;
#pragma unroll
        for (int c = 0; c < 8; ++c) {
            s += Ssum[tid * 8 + c];
            q += Ssq [tid * 8 + c];
        }
        atomicAdd(&sums[col0 + tid], s);
        atomicAdd(&sums[512 + col0 + tid], q);
    }
}

// ============ fallback small-ws kernel ============
template<int MODE>
__global__ __launch_bounds__(256)
void gemm_k(const float* __restrict__ mx, const float* __restrict__ Wm,
            double* __restrict__ hbuf, double* __restrict__ sums,
            const double* __restrict__ scale, const double* __restrict__ shiftv,
            const float* __restrict__ x, float* __restrict__ out)
{
    __shared__ __align__(16) char smem[LDS_BYTES];
    double (*Ald)[APITCH] = reinterpret_cast<double(*)[APITCH]>(smem);
    double (*Wld)[WPITCH] = reinterpret_cast<double(*)[WPITCH]>(smem + (size_t)BM * APITCH * 8);

    const int tid  = threadIdx.x;
    const int rb   = blockIdx.x >> 2;
    const int cb   = blockIdx.x & 3;
    const int row0 = rb * BM;
    const int col0 = cb * BNT;

    const int arow = tid >> 2;
    const int ak   = (tid & 3) * 8;
    const int erow = tid >> 1;
    const int wk   = (tid & 1) * 16;

    const float* aSrc = mx + (size_t)(row0 + arow) * DDIM;
    const float* wSrc = Wm + (size_t)(col0 + erow) * DDIM;

    const int rg = tid >> 4;
    const int cg = tid & 15;

    double acc[4][8];
#pragma unroll
    for (int i = 0; i < 4; ++i)
#pragma unroll
        for (int j = 0; j < 8; ++j) acc[i][j] = 0.0;

    for (int kk = 0; kk < DDIM; kk += BK) {
        const float4 a0 = *(const float4*)(aSrc + kk + ak);
        const float4 a1 = *(const float4*)(aSrc + kk + ak + 4);
        const float4 w0 = *(const float4*)(wSrc + kk + wk);
        const float4 w1 = *(const float4*)(wSrc + kk + wk + 4);
        const float4 w2 = *(const float4*)(wSrc + kk + wk + 8);
        const float4 w3 = *(const float4*)(wSrc + kk + wk + 12);
        __syncthreads();
        Ald[arow][ak + 0] = (double)a0.x; Ald[arow][ak + 1] = (double)a0.y;
        Ald[arow][ak + 2] = (double)a0.z; Ald[arow][ak + 3] = (double)a0.w;
        Ald[arow][ak + 4] = (double)a1.x; Ald[arow][ak + 5] = (double)a1.y;
        Ald[arow][ak + 6] = (double)a1.z; Ald[arow][ak + 7] = (double)a1.w;
        const float wfv[16] = {w0.x, w0.y, w0.z, w0.w, w1.x, w1.y, w1.z, w1.w,
                               w2.x, w2.y, w2.z, w2.w, w3.x, w3.y, w3.z, w3.w};
#pragma unroll
        for (int q = 0; q < 16; ++q) Wld[wk + q][erow] = (double)wfv[q];
        __syncthreads();

#pragma unroll 4
        for (int d = 0; d < BK; ++d) {
            double a[4], wv[8];
#pragma unroll
            for (int i = 0; i < 4; ++i) a[i] = Ald[rg * 4 + i][d];
#pragma unroll
            for (int j = 0; j < 8; ++j) wv[j] = Wld[d][cg * 8 + j];
#pragma unroll
            for (int i = 0; i < 4; ++i)
#pragma unroll
                for (int j = 0; j < 8; ++j)
                    acc[i][j] = fma(a[i], wv[j], acc[i][j]);
        }
    }

    if (MODE <= 1) {
        __syncthreads();
        double* scr = reinterpret_cast<double*>(smem);
#pragma unroll
        for (int j = 0; j < 8; ++j) {
            const double s = acc[0][j] + acc[1][j] + acc[2][j] + acc[3][j];
            const double q = acc[0][j]*acc[0][j] + acc[1][j]*acc[1][j]
                           + acc[2][j]*acc[2][j] + acc[3][j]*acc[3][j];
            scr[(cg * 8 + j) * 16 + rg] = s;
            scr[2048 + (cg * 8 + j) * 16 + rg] = q;
        }
        __syncthreads();
        if (tid < 128) {
            double s = 0.0, q = 0.0;
#pragma unroll
            for (int r = 0; r < 16; ++r) {
                s += scr[tid * 16 + r];
                q += scr[2048 + tid * 16 + r];
            }
            atomicAdd(&sums[col0 + tid], s);
            atomicAdd(&sums[512 + col0 + tid], q);
        }
    }

    if (MODE == 2) {
        const int p  = rb * 16 + rg;
        const int nn = p >> 6;
        const int bb = p & 63;
#pragma unroll
        for (int j = 0; j < 8; ++j) {
            const int e = col0 + cg * 8 + j;
            const double sc = scale[e];
            const double sh = shiftv[e];
            const size_t basex = (size_t)bb * (NDIM * DDIM) + (size_t)nn * DDIM + e;
            double v = 0.0;
#pragma unroll
            for (int t = 0; t < 4; ++t) {
                const double hn = fma(acc[t][j], sc, sh);
                v = v + (hn - v) / 2.0;
                const bool s = (v - 0.5) >= 0.0;
                const size_t xi = (size_t)t * BND + basex;
                out[xi] = s ? x[xi] : 0.0f;
                if (s) v = 0.0;
            }
        }
    }
}

__global__ void zero_k(double* sums)
{
    const int i = blockIdx.x * 256 + threadIdx.x;
    if (i < 1024) sums[i] = 0.0;
}

__global__ void stat_k(const double* __restrict__ sums,
                       const float* __restrict__ gamma, const float* __restrict__ beta,
                       double* __restrict__ scale, double* __restrict__ shiftv)
{
    const int e = blockIdx.x * 256 + threadIdx.x;
    if (e < 512) {
        const double mean = sums[e] * (1.0 / 65536.0);
        const double msq  = sums[512 + e] * (1.0 / 65536.0);
        const double var  = msq - mean * mean;
        const double inv  = 1.0 / sqrt(var + BN_EPS);
        const double g    = (double)gamma[e] * inv;
        scale[e]  = g;
        shiftv[e] = (double)beta[e] - mean * g;
    }
}

// LIF pass, 2 channels per thread (double2/float2 vectorized)
__global__ __launch_bounds__(256)
void lifh_k(const double* __restrict__ hbuf, const double* __restrict__ scale,
            const double* __restrict__ shiftv, const float* __restrict__ x,
            float* __restrict__ out)
{
    const size_t i = (size_t)blockIdx.x * 256 + threadIdx.x;   // < B*N*D/2
    const int e2 = (int)(i & 255) * 2;
    const size_t p = i >> 8;            // p = n*B + b
    const int nn = (int)(p >> 6);
    const int bb = (int)(p & 63);
    const double2 sc = *(const double2*)&scale[e2];
    const double2 sh = *(const double2*)&shiftv[e2];
    const double* hp = hbuf + p * 2048 + e2;
    const size_t basex = (size_t)bb * (NDIM * DDIM) + (size_t)nn * DDIM + e2;
    double v0 = 0.0, v1 = 0.0;
#pragma unroll
    for (int t = 0; t < 4; ++t) {
        const double2 h2 = *(const double2*)(hp + (size_t)t * 512);
        const double hn0 = fma(h2.x, sc.x, sh.x);
        const double hn1 = fma(h2.y, sc.y, sh.y);
        v0 = v0 + (hn0 - v0) / 2.0;
        v1 = v1 + (hn1 - v1) / 2.0;
        const bool s0 = (v0 - 0.5) >= 0.0;
        const bool s1 = (v1 - 0.5) >= 0.0;
        const size_t xi = (size_t)t * BND + basex;
        const float2 xv = *(const float2*)(x + xi);
        float2 ov;
        ov.x = s0 ? xv.x : 0.0f;
        ov.y = s1 ? xv.y : 0.0f;
        *(float2*)(out + xi) = ov;
        if (s0) v0 = 0.0;
        if (s1) v1 = 0.0;
    }
}

extern "C" void kernel_launch(void* const* d_in, const int* in_sizes, int n_in,
                              void* d_out, int out_size, void* d_ws, size_t ws_size,
                              hipStream_t stream)
{
    const float* x     = (const float*)d_in[0];
    const float* mx    = (const float*)d_in[1];
    const float* Wm    = (const float*)d_in[2];
    const float* gamma = (const float*)d_in[3];
    const float* beta  = (const float*)d_in[4];
    float* out = (float*)d_out;

    char* ws = (char*)d_ws;
    double* sums   = (double*)ws;             // [1024]
    double* scale  = (double*)(ws + 8192);    // [512]
    double* shiftv = scale + 512;             // [512]
    double* rowmap = (double*)(ws + 16384);   // [256]  (f64 path)
    double* irow8  = (double*)(ws + 18432);   // [1024] (i8 path)
    double* icol8  = (double*)(ws + 26624);   // [64]
    double* hbuf   = (double*)(ws + 32768);   // [65536*512] f64

    const size_t HBSZ   = (size_t)MROWS * DDIM * 8;          // 268435456
    const size_t OFF_AS = 32768 + HBSZ;                      // A slices
    const size_t ASSZ   = (size_t)NSA * APL;                 // 201326592
    const size_t OFF_WS = OFF_AS + ASSZ;
    const size_t WSSZ   = (size_t)NSW * WPL;                 // 1310720
    const size_t need8  = OFF_WS + WSSZ;                     // ~471.1 MB
    const size_t need_h = 32768 + HBSZ;                      // ~268.5 MB

    hipLaunchKernelGGL(zero_k, dim3(4), dim3(256), 0, stream, sums);

    if (ws_size >= need8) {
        char* Asl = ws + OFF_AS;
        char* Wsl = ws + OFF_WS;
        hipLaunchKernelGGL(probe8_k, dim3(1), dim3(64), 0, stream, irow8, icol8);
        hipLaunchKernelGGL(slice_a_k, dim3(1024), dim3(256), 0, stream, mx, Asl);
        hipLaunchKernelGGL(slice_w_k, dim3(64), dim3(256), 0, stream, Wm, Wsl);
        hipLaunchKernelGGL(gemm8_k, dim3(8192), dim3(256), 0, stream,
                           Asl, Wsl, hbuf, sums, irow8, icol8);
        hipLaunchKernelGGL(stat_k, dim3(2), dim3(256), 0, stream,
                           sums, gamma, beta, scale, shiftv);
        hipLaunchKernelGGL(lifh_k, dim3(16384), dim3(256), 0, stream,
                           hbuf, scale, shiftv, x, out);
    } else if (ws_size >= need_h) {
        hipLaunchKernelGGL(probe_k, dim3(1), dim3(64), 0, stream, rowmap);
        hipLaunchKernelGGL(gemm3_k, dim3(4096), dim3(256), 0, stream,
                           mx, Wm, hbuf, sums, rowmap);
        hipLaunchKernelGGL(stat_k, dim3(2), dim3(256), 0, stream,
                           sums, gamma, beta, scale, shiftv);
        hipLaunchKernelGGL(lifh_k, dim3(16384), dim3(256), 0, stream,
                           hbuf, scale, shiftv, x, out);
    } else {
        hipLaunchKernelGGL((gemm_k<0>), dim3(4096), dim3(256), 0, stream,
                           mx, Wm, nullptr, sums, nullptr, nullptr, nullptr, nullptr);
        hipLaunchKernelGGL(stat_k, dim3(2), dim3(256), 0, stream,
                           sums, gamma, beta, scale, shiftv);
        hipLaunchKernelGGL((gemm_k<2>), dim3(4096), dim3(256), 0, stream,
                           mx, Wm, nullptr, nullptr, scale, shiftv, x, out);
    }
}